// Round 2
// baseline (2503.651 us; speedup 1.0000x reference)
//
#include <hip/hip_runtime.h>
#include <hip/hip_bf16.h>

#define NN 200000
#define NE 600000
#define NG 10000

typedef __attribute__((ext_vector_type(8))) short bfrag;
typedef __attribute__((ext_vector_type(4))) float f32x4;
typedef unsigned short u16;

static __device__ __forceinline__ u16 f2b(float x) {
  __hip_bfloat16 b = __float2bfloat16(x);
  return __builtin_bit_cast(u16, b);
}
static __device__ __forceinline__ float b2f(u16 u) {
  __hip_bfloat16 b = __builtin_bit_cast(__hip_bfloat16, u);
  return __bfloat162float(b);
}
static __device__ __forceinline__ void split(float v, u16& hi, u16& lo) {
  hi = f2b(v);
  lo = f2b(v - b2f(hi));
}

// ---------------- weight prep: per-lane MFMA B-fragments, bf16 hi+lo ------
// wf layout (u16):
//  [0,12288)        L0 G1 hi (8ct x 3kk x 64lane x 8)   [12288,24576) lo
//  [24576,40960)    L0 G2 hi (8x4x64x8)                 [40960,57344) lo
//  layer j (0..3): base=57344+j*65536
//    G1 hi base, lo +16384; G2 hi +32768, lo +49152
__global__ void prep_kernel(const float* __restrict__ W1_0, const float* __restrict__ W2_0,
                            const float* __restrict__ W1s, const float* __restrict__ W2s,
                            u16* __restrict__ wf) {
  int i = blockIdx.x * 256 + threadIdx.x;
  if (i >= 312 * 64) return;
  int t = i >> 6, lane = i & 63;
  const float* W;
  int KS, ct, kk, Krows, base, half;
  if (t < 24) {
    W = W1_0; KS = 3; ct = t / 3; kk = t - ct * 3; Krows = 78; base = 0; half = 12288;
  } else if (t < 56) {
    int u = t - 24;
    W = W2_0; KS = 4; ct = u >> 2; kk = u & 3; Krows = 128; base = 24576; half = 16384;
  } else {
    int u = t - 56;
    int j = u >> 6, r = u & 63;
    KS = 4; Krows = 128; half = 16384;
    if (r < 32) {
      W = W1s + j * 16384; ct = r >> 2; kk = r & 3; base = 57344 + j * 65536;
    } else {
      W = W2s + j * 16384; r -= 32; ct = r >> 2; kk = r & 3; base = 57344 + j * 65536 + 32768;
    }
  }
  int col = ct * 16 + (lane & 15);
  int idx = ((ct * KS + kk) * 64 + lane) * 8;
  for (int jj = 0; jj < 8; jj++) {
    int k = kk * 32 + 8 * (lane >> 4) + jj;
    float v = (k < Krows) ? W[k * 128 + col] : 0.f;
    u16 hi, lo;
    split(v, hi, lo);
    wf[base + idx + jj] = hi;
    wf[base + half + idx + jj] = lo;
  }
}

// ---------------- aggregation: scatter-add (BN applied on gather, f32) ----
template <bool FIRST>
__global__ void agg_kernel(const int* __restrict__ src, const int* __restrict__ dst,
                           const float* __restrict__ x, const float* __restrict__ h,
                           const float* __restrict__ ss, float* __restrict__ agg) {
  constexpr int D = FIRST ? 78 : 128;
  const int total = NE * D;
  for (int i = blockIdx.x * blockDim.x + threadIdx.x; i < total; i += gridDim.x * blockDim.x) {
    int e, f;
    if (FIRST) { e = i / 78; f = i - e * 78; } else { e = i >> 7; f = i & 127; }
    int s = src[e], d = dst[e];
    float v = FIRST ? x[s * 78 + f] : h[s * 128 + f] * ss[f] + ss[128 + f];
    atomicAdd(&agg[d * D + f], v);
  }
}

// ---------------- fused MLP block: split-precision MFMA x2 + BN stats -----
// 256 threads (4 waves), 64 rows/block. LDS: A_hi|A_lo|T_hi|T_lo (stride 136)
// NOTE: hout may alias agg (same rows only; agg fully consumed before write).
template <bool FIRST>
__global__ __launch_bounds__(256, 2) void mlp_kernel(
    const float* __restrict__ xin, const float* __restrict__ hin,
    const float* __restrict__ ss, const float* __restrict__ agg,
    const u16* __restrict__ w1hi, const u16* __restrict__ w1lo,
    const u16* __restrict__ w2hi, const u16* __restrict__ w2lo,
    const float* __restrict__ b1, const float* __restrict__ b2,
    float* __restrict__ hout, float* __restrict__ stats) {
  constexpr int KS1 = FIRST ? 3 : 4;
  constexpr int AH = 0, AL = 8704, TH = 17408, TL = 26112;
  __shared__ u16 lds[34816];
  __shared__ float sst[256];
  const int tid = threadIdx.x;
  const int rows0 = blockIdx.x * 64;
  sst[tid] = 0.f;

  // ---- stage A = h_bn + agg as bf16 hi/lo ----
  if (FIRST) {
    for (int i = tid; i < 64 * 96; i += 256) {
      int r = i / 96, k = i - r * 96;
      float v = 0.f;
      if (k < 78) {
        int g = rows0 + r;
        v = xin[g * 78 + k] + agg[g * 78 + k];
      }
      u16 hi, lo;
      split(v, hi, lo);
      lds[AH + r * 136 + k] = hi;
      lds[AL + r * 136 + k] = lo;
    }
  } else {
    for (int i = tid; i < 64 * 32; i += 256) {
      int r = i >> 5, k4 = (i & 31) * 4;
      int g = rows0 + r;
      const float4 a4 = *reinterpret_cast<const float4*>(&agg[g * 128 + k4]);
      const float4 h4 = *reinterpret_cast<const float4*>(&hin[g * 128 + k4]);
      float v0 = h4.x * ss[k4 + 0] + ss[128 + k4 + 0] + a4.x;
      float v1 = h4.y * ss[k4 + 1] + ss[128 + k4 + 1] + a4.y;
      float v2 = h4.z * ss[k4 + 2] + ss[128 + k4 + 2] + a4.z;
      float v3 = h4.w * ss[k4 + 3] + ss[128 + k4 + 3] + a4.w;
      ushort4 oh, ol;
      split(v0, oh.x, ol.x);
      split(v1, oh.y, ol.y);
      split(v2, oh.z, ol.z);
      split(v3, oh.w, ol.w);
      *reinterpret_cast<ushort4*>(&lds[AH + r * 136 + k4]) = oh;
      *reinterpret_cast<ushort4*>(&lds[AL + r * 136 + k4]) = ol;
    }
  }
  __syncthreads();

  const int w = tid >> 6, l = tid & 63;
  const int l15 = l & 15, lg = l >> 4;
  const int arow = (16 * w + l15) * 136 + 8 * lg;

  // ---- GEMM1: T = relu(A @ W1 + b1), split precision ----
  bfrag ahi[KS1], alo[KS1];
#pragma unroll
  for (int kk = 0; kk < KS1; kk++) {
    ahi[kk] = *reinterpret_cast<const bfrag*>(&lds[AH + arow + kk * 32]);
    alo[kk] = *reinterpret_cast<const bfrag*>(&lds[AL + arow + kk * 32]);
  }
#pragma unroll
  for (int ct = 0; ct < 8; ct++) {
    float bb = b1[ct * 16 + l15];
    f32x4 acc = {bb, bb, bb, bb};
#pragma unroll
    for (int kk = 0; kk < KS1; kk++) {
      int fi = ((ct * KS1 + kk) * 64 + l) * 8;
      bfrag whi = *reinterpret_cast<const bfrag*>(&w1hi[fi]);
      bfrag wlo = *reinterpret_cast<const bfrag*>(&w1lo[fi]);
      acc = __builtin_amdgcn_mfma_f32_16x16x32_bf16(alo[kk], whi, acc, 0, 0, 0);
      acc = __builtin_amdgcn_mfma_f32_16x16x32_bf16(ahi[kk], wlo, acc, 0, 0, 0);
      acc = __builtin_amdgcn_mfma_f32_16x16x32_bf16(ahi[kk], whi, acc, 0, 0, 0);
    }
#pragma unroll
    for (int r = 0; r < 4; r++) {
      float v = fmaxf(acc[r], 0.f);
      u16 hi, lo;
      split(v, hi, lo);
      int off = (16 * w + 4 * lg + r) * 136 + ct * 16 + l15;
      lds[TH + off] = hi;
      lds[TL + off] = lo;
    }
  }
  __syncthreads();

  // ---- GEMM2: U = relu(T @ W2 + b2), write f32 h, BN stats ----
  bfrag thi[4], tlo[4];
#pragma unroll
  for (int kk = 0; kk < 4; kk++) {
    thi[kk] = *reinterpret_cast<const bfrag*>(&lds[TH + arow + kk * 32]);
    tlo[kk] = *reinterpret_cast<const bfrag*>(&lds[TL + arow + kk * 32]);
  }
#pragma unroll
  for (int ct = 0; ct < 8; ct++) {
    float bb = b2[ct * 16 + l15];
    f32x4 acc = {bb, bb, bb, bb};
#pragma unroll
    for (int kk = 0; kk < 4; kk++) {
      int fi = ((ct * 4 + kk) * 64 + l) * 8;
      bfrag whi = *reinterpret_cast<const bfrag*>(&w2hi[fi]);
      bfrag wlo = *reinterpret_cast<const bfrag*>(&w2lo[fi]);
      acc = __builtin_amdgcn_mfma_f32_16x16x32_bf16(tlo[kk], whi, acc, 0, 0, 0);
      acc = __builtin_amdgcn_mfma_f32_16x16x32_bf16(thi[kk], wlo, acc, 0, 0, 0);
      acc = __builtin_amdgcn_mfma_f32_16x16x32_bf16(thi[kk], whi, acc, 0, 0, 0);
    }
    float s = 0.f, q = 0.f;
#pragma unroll
    for (int r = 0; r < 4; r++) {
      float v = fmaxf(acc[r], 0.f);
      hout[(size_t)(rows0 + 16 * w + 4 * lg + r) * 128 + ct * 16 + l15] = v;
      s += v;
      q += v * v;
    }
    s += __shfl_xor(s, 16); s += __shfl_xor(s, 32);
    q += __shfl_xor(q, 16); q += __shfl_xor(q, 32);
    if (lg == 0) {
      atomicAdd(&sst[ct * 16 + l15], s);
      atomicAdd(&sst[128 + ct * 16 + l15], q);
    }
  }
  __syncthreads();
  atomicAdd(&stats[tid], sst[tid]);
}

// ---------------- BN finalize: scale/shift from sum/sumsq -----------------
__global__ void bn_kernel(const float* __restrict__ stats, const float* __restrict__ gamma,
                          const float* __restrict__ beta, float* __restrict__ ss) {
  int c = threadIdx.x;  // 128 threads
  float mean = stats[c] * (1.f / NN);
  float var = stats[128 + c] * (1.f / NN) - mean * mean;
  var = fmaxf(var, 0.f);
  float sc = gamma[c] * rsqrtf(var + 1e-5f);
  ss[c] = sc;
  ss[128 + c] = beta[c] - mean * sc;
}

// ---------------- graph pooling: BN-inline segment sum --------------------
__global__ void pool_kernel(const float* __restrict__ h, const float* __restrict__ ss,
                            const int* __restrict__ batch, float* __restrict__ pooled) {
  const int total = NN * 32;
  for (int i = blockIdx.x * blockDim.x + threadIdx.x; i < total; i += gridDim.x * blockDim.x) {
    int n = i >> 5, c4 = (i & 31) * 4;
    int g = batch[n];
    const float4 h4 = *reinterpret_cast<const float4*>(&h[n * 128 + c4]);
    atomicAdd(&pooled[g * 128 + c4 + 0], h4.x * ss[c4 + 0] + ss[128 + c4 + 0]);
    atomicAdd(&pooled[g * 128 + c4 + 1], h4.y * ss[c4 + 1] + ss[128 + c4 + 1]);
    atomicAdd(&pooled[g * 128 + c4 + 2], h4.z * ss[c4 + 2] + ss[128 + c4 + 2]);
    atomicAdd(&pooled[g * 128 + c4 + 3], h4.w * ss[c4 + 3] + ss[128 + c4 + 3]);
  }
}

// ---------------- final FC: out = relu(pooled @ fcW + fcb) ----------------
__global__ void fc_kernel(const float* __restrict__ pooled, const float* __restrict__ fcW,
                          const float* __restrict__ fcb, float* __restrict__ out) {
  int i = blockIdx.x * 256 + threadIdx.x;
  if (i >= NG * 64) return;
  int g = i >> 6, o = i & 63;
  float acc = fcb[o];
#pragma unroll 8
  for (int k = 0; k < 128; k++) acc += pooled[g * 128 + k] * fcW[k * 64 + o];
  out[i] = fmaxf(acc, 0.f);
}

extern "C" void kernel_launch(void* const* d_in, const int* in_sizes, int n_in,
                              void* d_out, int out_size, void* d_ws, size_t ws_size,
                              hipStream_t stream) {
  const float* x = (const float*)d_in[0];
  const int* ei = (const int*)d_in[1];
  const int* src = ei;
  const int* dst = ei + NE;
  const int* batch = (const int*)d_in[2];
  const float* W1_0 = (const float*)d_in[3];
  const float* b1_0 = (const float*)d_in[4];
  const float* W2_0 = (const float*)d_in[5];
  const float* b2_0 = (const float*)d_in[6];
  const float* g_0 = (const float*)d_in[7];
  const float* be_0 = (const float*)d_in[8];
  const float* W1s = (const float*)d_in[9];
  const float* b1s = (const float*)d_in[10];
  const float* W2s = (const float*)d_in[11];
  const float* b2s = (const float*)d_in[12];
  const float* gs = (const float*)d_in[13];
  const float* bes = (const float*)d_in[14];
  const float* fcW = (const float*)d_in[15];
  const float* fcb = (const float*)d_in[16];

  char* ws = (char*)d_ws;
  float* buf0 = (float*)(ws + 0);                          // 102,400,000 B
  float* buf1 = (float*)(ws + 102400000);                  // 102,400,000 B
  float* POOLED = (float*)(ws + 204800000);                // 5,120,000 B
  float* STATS = (float*)(ws + 209920000);                 // 1,024 B
  float* SS = (float*)(ws + 209921024);                    // 1,024 B
  u16* WF = (u16*)(ws + 209922048);                        // 638,976 B

  prep_kernel<<<78, 256, 0, stream>>>(W1_0, W2_0, W1s, W2s, WF);

  float* buf[2] = {buf0, buf1};
  // ---- layer 0: agg(x) -> buf1 (78 cols); h0 -> buf0 ----
  hipMemsetAsync(buf1, 0, (size_t)NN * 78 * 4, stream);
  hipMemsetAsync(STATS, 0, 1024, stream);
  agg_kernel<true><<<4096, 256, 0, stream>>>(src, dst, x, nullptr, nullptr, buf1);
  mlp_kernel<true><<<3125, 256, 0, stream>>>(x, nullptr, nullptr, buf1,
                                             WF, WF + 12288, WF + 24576, WF + 40960,
                                             b1_0, b2_0, buf0, STATS);
  bn_kernel<<<1, 128, 0, stream>>>(STATS, g_0, be_0, SS);

  // ---- layers 1..4: hin = buf[(L+1)&1], agg+hout = buf[L&1] ----
  for (int L = 1; L < 5; L++) {
    int j = L - 1;
    const float* hin = buf[(L + 1) & 1];
    float* hb = buf[L & 1];
    hipMemsetAsync(hb, 0, (size_t)NN * 128 * 4, stream);
    hipMemsetAsync(STATS, 0, 1024, stream);
    agg_kernel<false><<<4096, 256, 0, stream>>>(src, dst, nullptr, hin, SS, hb);
    const u16* wl = WF + 57344 + j * 65536;
    mlp_kernel<false><<<3125, 256, 0, stream>>>(nullptr, hin, SS, hb,
                                                wl, wl + 16384, wl + 32768, wl + 49152,
                                                b1s + j * 128, b2s + j * 128, hb, STATS);
    bn_kernel<<<1, 128, 0, stream>>>(STATS, gs + j * 128, bes + j * 128, SS);
  }

  hipMemsetAsync(POOLED, 0, (size_t)NG * 128 * 4, stream);
  pool_kernel<<<2048, 256, 0, stream>>>(buf[0], SS, batch, POOLED);
  fc_kernel<<<(NG * 64 + 255) / 256, 256, 0, stream>>>(POOLED, fcW, fcb, (float*)d_out);
}

// Round 3
// 1331.267 us; speedup vs baseline: 1.8807x; 1.8807x over previous
//
#include <hip/hip_runtime.h>
#include <hip/hip_bf16.h>

#define NN 200000
#define NE 600000
#define NG 10000
#define NCH 98  // scan chunks of 2048 covering NN

typedef __attribute__((ext_vector_type(8))) short bfrag;
typedef __attribute__((ext_vector_type(4))) float f32x4;
typedef unsigned short u16;

static __device__ __forceinline__ u16 f2b(float x) {
  __hip_bfloat16 b = __float2bfloat16(x);
  return __builtin_bit_cast(u16, b);
}
static __device__ __forceinline__ float b2f(u16 u) {
  __hip_bfloat16 b = __builtin_bit_cast(__hip_bfloat16, u);
  return __bfloat162float(b);
}
static __device__ __forceinline__ void split(float v, u16& hi, u16& lo) {
  hi = f2b(v);
  lo = f2b(v - b2f(hi));
}

// ---------------- weight prep: per-lane MFMA B-fragments, bf16 hi+lo ------
__global__ void prep_kernel(const float* __restrict__ W1_0, const float* __restrict__ W2_0,
                            const float* __restrict__ W1s, const float* __restrict__ W2s,
                            u16* __restrict__ wf) {
  int i = blockIdx.x * 256 + threadIdx.x;
  if (i >= 312 * 64) return;
  int t = i >> 6, lane = i & 63;
  const float* W;
  int KS, ct, kk, Krows, base, half;
  if (t < 24) {
    W = W1_0; KS = 3; ct = t / 3; kk = t - ct * 3; Krows = 78; base = 0; half = 12288;
  } else if (t < 56) {
    int u = t - 24;
    W = W2_0; KS = 4; ct = u >> 2; kk = u & 3; Krows = 128; base = 24576; half = 16384;
  } else {
    int u = t - 56;
    int j = u >> 6, r = u & 63;
    KS = 4; Krows = 128; half = 16384;
    if (r < 32) {
      W = W1s + j * 16384; ct = r >> 2; kk = r & 3; base = 57344 + j * 65536;
    } else {
      W = W2s + j * 16384; r -= 32; ct = r >> 2; kk = r & 3; base = 57344 + j * 65536 + 32768;
    }
  }
  int col = ct * 16 + (lane & 15);
  int idx = ((ct * KS + kk) * 64 + lane) * 8;
  for (int jj = 0; jj < 8; jj++) {
    int k = kk * 32 + 8 * (lane >> 4) + jj;
    float v = (k < Krows) ? W[k * 128 + col] : 0.f;
    u16 hi, lo;
    split(v, hi, lo);
    wf[base + idx + jj] = hi;
    wf[base + half + idx + jj] = lo;
  }
}

// ---------------- CSR build: histogram + scan + scatter -------------------
__global__ void hist_kernel(const int* __restrict__ dst, int* __restrict__ deg) {
  int e = blockIdx.x * 256 + threadIdx.x;
  if (e < NE) atomicAdd(&deg[dst[e]], 1);
}

__global__ void scan1_kernel(const int* __restrict__ deg, int* __restrict__ csum) {
  __shared__ int s[256];
  int base = blockIdx.x * 2048 + threadIdx.x * 8;
  int t = 0;
#pragma unroll
  for (int j = 0; j < 8; j++) {
    int idx = base + j;
    if (idx < NN) t += deg[idx];
  }
  s[threadIdx.x] = t;
  __syncthreads();
  for (int o = 128; o > 0; o >>= 1) {
    if (threadIdx.x < o) s[threadIdx.x] += s[threadIdx.x + o];
    __syncthreads();
  }
  if (threadIdx.x == 0) csum[blockIdx.x] = s[0];
}

__global__ void scan2_kernel(int* __restrict__ csum, int* __restrict__ rowptr) {
  int acc = 0;
  for (int i = 0; i < NCH; i++) {
    int v = csum[i];
    csum[i] = acc;
    acc += v;
  }
  rowptr[NN] = acc;  // == NE
}

// NOTE: deg and cursor may alias (each index read-then-written by one thread).
__global__ void scan3_kernel(const int* deg, const int* __restrict__ csum,
                             int* __restrict__ rowptr, int* cursor) {
  __shared__ int s[256];
  int tid = threadIdx.x;
  int base = blockIdx.x * 2048 + tid * 8;
  int loc[8];
  int t = 0;
#pragma unroll
  for (int j = 0; j < 8; j++) {
    int idx = base + j;
    int d = (idx < NN) ? deg[idx] : 0;
    loc[j] = t;
    t += d;
  }
  s[tid] = t;
  __syncthreads();
  for (int o = 1; o < 256; o <<= 1) {
    int u = (tid >= o) ? s[tid - o] : 0;
    __syncthreads();
    s[tid] += u;
    __syncthreads();
  }
  int off = csum[blockIdx.x] + s[tid] - t;
#pragma unroll
  for (int j = 0; j < 8; j++) {
    int idx = base + j;
    if (idx < NN) {
      int r = off + loc[j];
      rowptr[idx] = r;
      cursor[idx] = r;
    }
  }
}

__global__ void scatter_kernel(const int* __restrict__ src, const int* __restrict__ dst,
                               int* __restrict__ cursor, int* __restrict__ csr_src) {
  int e = blockIdx.x * 256 + threadIdx.x;
  if (e < NE) {
    int p = atomicAdd(&cursor[dst[e]], 1);
    csr_src[p] = src[e];
  }
}

// ---------------- aggregation: CSR gather-sum, one wave per node ----------
template <bool FIRST>
__global__ void agg_csr_kernel(const int* __restrict__ rowptr, const int* __restrict__ csr_src,
                               const float* __restrict__ x, const float* __restrict__ h,
                               const float* __restrict__ ss, float* __restrict__ agg) {
  int node = blockIdx.x * 4 + (threadIdx.x >> 6);
  int lane = threadIdx.x & 63;
  if (node >= NN) return;
  int beg = rowptr[node], end = rowptr[node + 1];
  int f0 = 2 * lane;
  if (FIRST) {
    if (f0 >= 78) return;
    float a0 = 0.f, a1 = 0.f;
    for (int i = beg; i < end; i++) {
      int s = csr_src[i];
      const float2 v = *reinterpret_cast<const float2*>(&x[(size_t)s * 78 + f0]);
      a0 += v.x;
      a1 += v.y;
    }
    float2 o = {a0, a1};
    *reinterpret_cast<float2*>(&agg[(size_t)node * 78 + f0]) = o;
  } else {
    float a0 = 0.f, a1 = 0.f;
    for (int i = beg; i < end; i++) {
      int s = csr_src[i];
      const float2 v = *reinterpret_cast<const float2*>(&h[(size_t)s * 128 + f0]);
      a0 += v.x;
      a1 += v.y;
    }
    float cnt = (float)(end - beg);
    float2 o;
    o.x = a0 * ss[f0] + cnt * ss[128 + f0];
    o.y = a1 * ss[f0 + 1] + cnt * ss[128 + f0 + 1];
    *reinterpret_cast<float2*>(&agg[(size_t)node * 128 + f0]) = o;
  }
}

// ---------------- fused MLP block: split-precision MFMA x2 + BN stats -----
// NOTE: hout may alias agg (same rows only; agg fully consumed before write).
template <bool FIRST>
__global__ __launch_bounds__(256, 2) void mlp_kernel(
    const float* __restrict__ xin, const float* __restrict__ hin,
    const float* __restrict__ ss, const float* __restrict__ agg,
    const u16* __restrict__ w1hi, const u16* __restrict__ w1lo,
    const u16* __restrict__ w2hi, const u16* __restrict__ w2lo,
    const float* __restrict__ b1, const float* __restrict__ b2,
    float* __restrict__ hout, float* __restrict__ stats) {
  constexpr int KS1 = FIRST ? 3 : 4;
  constexpr int AH = 0, AL = 8704, TH = 17408, TL = 26112;
  __shared__ u16 lds[34816];
  __shared__ float sst[256];
  const int tid = threadIdx.x;
  const int rows0 = blockIdx.x * 64;
  sst[tid] = 0.f;

  if (FIRST) {
    for (int i = tid; i < 64 * 96; i += 256) {
      int r = i / 96, k = i - r * 96;
      float v = 0.f;
      if (k < 78) {
        int g = rows0 + r;
        v = xin[g * 78 + k] + agg[g * 78 + k];
      }
      u16 hi, lo;
      split(v, hi, lo);
      lds[AH + r * 136 + k] = hi;
      lds[AL + r * 136 + k] = lo;
    }
  } else {
    for (int i = tid; i < 64 * 32; i += 256) {
      int r = i >> 5, k4 = (i & 31) * 4;
      int g = rows0 + r;
      const float4 a4 = *reinterpret_cast<const float4*>(&agg[g * 128 + k4]);
      const float4 h4 = *reinterpret_cast<const float4*>(&hin[g * 128 + k4]);
      float v0 = h4.x * ss[k4 + 0] + ss[128 + k4 + 0] + a4.x;
      float v1 = h4.y * ss[k4 + 1] + ss[128 + k4 + 1] + a4.y;
      float v2 = h4.z * ss[k4 + 2] + ss[128 + k4 + 2] + a4.z;
      float v3 = h4.w * ss[k4 + 3] + ss[128 + k4 + 3] + a4.w;
      ushort4 oh, ol;
      split(v0, oh.x, ol.x);
      split(v1, oh.y, ol.y);
      split(v2, oh.z, ol.z);
      split(v3, oh.w, ol.w);
      *reinterpret_cast<ushort4*>(&lds[AH + r * 136 + k4]) = oh;
      *reinterpret_cast<ushort4*>(&lds[AL + r * 136 + k4]) = ol;
    }
  }
  __syncthreads();

  const int w = tid >> 6, l = tid & 63;
  const int l15 = l & 15, lg = l >> 4;
  const int arow = (16 * w + l15) * 136 + 8 * lg;

  bfrag ahi[KS1], alo[KS1];
#pragma unroll
  for (int kk = 0; kk < KS1; kk++) {
    ahi[kk] = *reinterpret_cast<const bfrag*>(&lds[AH + arow + kk * 32]);
    alo[kk] = *reinterpret_cast<const bfrag*>(&lds[AL + arow + kk * 32]);
  }
#pragma unroll
  for (int ct = 0; ct < 8; ct++) {
    float bb = b1[ct * 16 + l15];
    f32x4 acc = {bb, bb, bb, bb};
#pragma unroll
    for (int kk = 0; kk < KS1; kk++) {
      int fi = ((ct * KS1 + kk) * 64 + l) * 8;
      bfrag whi = *reinterpret_cast<const bfrag*>(&w1hi[fi]);
      bfrag wlo = *reinterpret_cast<const bfrag*>(&w1lo[fi]);
      acc = __builtin_amdgcn_mfma_f32_16x16x32_bf16(alo[kk], whi, acc, 0, 0, 0);
      acc = __builtin_amdgcn_mfma_f32_16x16x32_bf16(ahi[kk], wlo, acc, 0, 0, 0);
      acc = __builtin_amdgcn_mfma_f32_16x16x32_bf16(ahi[kk], whi, acc, 0, 0, 0);
    }
#pragma unroll
    for (int r = 0; r < 4; r++) {
      float v = fmaxf(acc[r], 0.f);
      u16 hi, lo;
      split(v, hi, lo);
      int off = (16 * w + 4 * lg + r) * 136 + ct * 16 + l15;
      lds[TH + off] = hi;
      lds[TL + off] = lo;
    }
  }
  __syncthreads();

  bfrag thi[4], tlo[4];
#pragma unroll
  for (int kk = 0; kk < 4; kk++) {
    thi[kk] = *reinterpret_cast<const bfrag*>(&lds[TH + arow + kk * 32]);
    tlo[kk] = *reinterpret_cast<const bfrag*>(&lds[TL + arow + kk * 32]);
  }
#pragma unroll
  for (int ct = 0; ct < 8; ct++) {
    float bb = b2[ct * 16 + l15];
    f32x4 acc = {bb, bb, bb, bb};
#pragma unroll
    for (int kk = 0; kk < 4; kk++) {
      int fi = ((ct * 4 + kk) * 64 + l) * 8;
      bfrag whi = *reinterpret_cast<const bfrag*>(&w2hi[fi]);
      bfrag wlo = *reinterpret_cast<const bfrag*>(&w2lo[fi]);
      acc = __builtin_amdgcn_mfma_f32_16x16x32_bf16(tlo[kk], whi, acc, 0, 0, 0);
      acc = __builtin_amdgcn_mfma_f32_16x16x32_bf16(thi[kk], wlo, acc, 0, 0, 0);
      acc = __builtin_amdgcn_mfma_f32_16x16x32_bf16(thi[kk], whi, acc, 0, 0, 0);
    }
    float s = 0.f, q = 0.f;
#pragma unroll
    for (int r = 0; r < 4; r++) {
      float v = fmaxf(acc[r], 0.f);
      hout[(size_t)(rows0 + 16 * w + 4 * lg + r) * 128 + ct * 16 + l15] = v;
      s += v;
      q += v * v;
    }
    s += __shfl_xor(s, 16); s += __shfl_xor(s, 32);
    q += __shfl_xor(q, 16); q += __shfl_xor(q, 32);
    if (lg == 0) {
      atomicAdd(&sst[ct * 16 + l15], s);
      atomicAdd(&sst[128 + ct * 16 + l15], q);
    }
  }
  __syncthreads();
  atomicAdd(&stats[tid], sst[tid]);
}

// ---------------- BN finalize -------------------------------------------
__global__ void bn_kernel(const float* __restrict__ stats, const float* __restrict__ gamma,
                          const float* __restrict__ beta, float* __restrict__ ss) {
  int c = threadIdx.x;  // 128 threads
  float mean = stats[c] * (1.f / NN);
  float var = stats[128 + c] * (1.f / NN) - mean * mean;
  var = fmaxf(var, 0.f);
  float sc = gamma[c] * rsqrtf(var + 1e-5f);
  ss[c] = sc;
  ss[128 + c] = beta[c] - mean * sc;
}

// ---------------- pooling: run-based segmented sum (batch is sorted) ------
__global__ void pool_kernel(const float* __restrict__ h, const float* __restrict__ ss,
                            const int* __restrict__ batch, float* __restrict__ pooled) {
  int c = threadIdx.x;  // 128 threads, one feature each
  int n0 = blockIdx.x * 128;
  int n1 = min(n0 + 128, NN);
  float sc = ss[c], sh = ss[128 + c];
  float acc = 0.f;
  float cnt = 0.f;
  int gprev = batch[n0];
  for (int n = n0; n < n1; n++) {
    int g = batch[n];
    if (g != gprev) {
      atomicAdd(&pooled[gprev * 128 + c], sc * acc + cnt * sh);
      acc = 0.f;
      cnt = 0.f;
      gprev = g;
    }
    acc += h[(size_t)n * 128 + c];
    cnt += 1.f;
  }
  atomicAdd(&pooled[gprev * 128 + c], sc * acc + cnt * sh);
}

// ---------------- final FC ------------------------------------------------
__global__ void fc_kernel(const float* __restrict__ pooled, const float* __restrict__ fcW,
                          const float* __restrict__ fcb, float* __restrict__ out) {
  int i = blockIdx.x * 256 + threadIdx.x;
  if (i >= NG * 64) return;
  int g = i >> 6, o = i & 63;
  float acc = fcb[o];
#pragma unroll 8
  for (int k = 0; k < 128; k++) acc += pooled[g * 128 + k] * fcW[k * 64 + o];
  out[i] = fmaxf(acc, 0.f);
}

extern "C" void kernel_launch(void* const* d_in, const int* in_sizes, int n_in,
                              void* d_out, int out_size, void* d_ws, size_t ws_size,
                              hipStream_t stream) {
  const float* x = (const float*)d_in[0];
  const int* ei = (const int*)d_in[1];
  const int* src = ei;
  const int* dst = ei + NE;
  const int* batch = (const int*)d_in[2];
  const float* W1_0 = (const float*)d_in[3];
  const float* b1_0 = (const float*)d_in[4];
  const float* W2_0 = (const float*)d_in[5];
  const float* b2_0 = (const float*)d_in[6];
  const float* g_0 = (const float*)d_in[7];
  const float* be_0 = (const float*)d_in[8];
  const float* W1s = (const float*)d_in[9];
  const float* b1s = (const float*)d_in[10];
  const float* W2s = (const float*)d_in[11];
  const float* b2s = (const float*)d_in[12];
  const float* gs = (const float*)d_in[13];
  const float* bes = (const float*)d_in[14];
  const float* fcW = (const float*)d_in[15];
  const float* fcb = (const float*)d_in[16];

  char* ws = (char*)d_ws;
  float* buf0 = (float*)(ws + 0);                   // 102,400,000 B
  float* buf1 = (float*)(ws + 102400000);           // 102,400,000 B
  float* POOLED = (float*)(ws + 204800000);         // 5,120,000 B
  float* STATS = (float*)(ws + 209920000);          // 1,024 B
  float* SS = (float*)(ws + 209921024);             // 1,024 B
  u16* WF = (u16*)(ws + 209922048);                 // 638,976 B
  int* ROWPTR = (int*)(ws + 210561024);             // 800,016 B
  int* CURSOR = (int*)(ws + 211361040);             // 800,000 B (also deg scratch)
  int* CSRC = (int*)(ws + 212161040);               // 2,400,000 B
  int* CSUM = (int*)(ws + 214561040);               // 512 B

  prep_kernel<<<78, 256, 0, stream>>>(W1_0, W2_0, W1s, W2s, WF);

  // ---- CSR build (once per launch; reused by all 5 layers) ----
  hipMemsetAsync(CURSOR, 0, NN * 4, stream);
  hist_kernel<<<(NE + 255) / 256, 256, 0, stream>>>(dst, CURSOR);
  scan1_kernel<<<NCH, 256, 0, stream>>>(CURSOR, CSUM);
  scan2_kernel<<<1, 1, 0, stream>>>(CSUM, ROWPTR);
  scan3_kernel<<<NCH, 256, 0, stream>>>(CURSOR, CSUM, ROWPTR, CURSOR);
  scatter_kernel<<<(NE + 255) / 256, 256, 0, stream>>>(src, dst, CURSOR, CSRC);

  float* buf[2] = {buf0, buf1};
  // ---- layer 0: agg(x) -> buf1 (78 cols); h0 -> buf0 ----
  hipMemsetAsync(STATS, 0, 1024, stream);
  agg_csr_kernel<true><<<(NN + 3) / 4, 256, 0, stream>>>(ROWPTR, CSRC, x, nullptr, nullptr, buf1);
  mlp_kernel<true><<<3125, 256, 0, stream>>>(x, nullptr, nullptr, buf1,
                                             WF, WF + 12288, WF + 24576, WF + 40960,
                                             b1_0, b2_0, buf0, STATS);
  bn_kernel<<<1, 128, 0, stream>>>(STATS, g_0, be_0, SS);

  // ---- layers 1..4 ----
  for (int L = 1; L < 5; L++) {
    int j = L - 1;
    const float* hin = buf[(L + 1) & 1];
    float* hb = buf[L & 1];
    hipMemsetAsync(STATS, 0, 1024, stream);
    agg_csr_kernel<false><<<(NN + 3) / 4, 256, 0, stream>>>(ROWPTR, CSRC, nullptr, hin, SS, hb);
    const u16* wl = WF + 57344 + j * 65536;
    mlp_kernel<false><<<3125, 256, 0, stream>>>(nullptr, hin, SS, hb,
                                                wl, wl + 16384, wl + 32768, wl + 49152,
                                                b1s + j * 128, b2s + j * 128, hb, STATS);
    bn_kernel<<<1, 128, 0, stream>>>(STATS, gs + j * 128, bes + j * 128, SS);
  }

  hipMemsetAsync(POOLED, 0, (size_t)NG * 128 * 4, stream);
  pool_kernel<<<(NN + 127) / 128, 128, 0, stream>>>(buf[0], SS, batch, POOLED);
  fc_kernel<<<(NG * 64 + 255) / 256, 256, 0, stream>>>(POOLED, fcW, fcb, (float*)d_out);
}

// Round 4
// 921.723 us; speedup vs baseline: 2.7163x; 1.4443x over previous
//
#include <hip/hip_runtime.h>
#include <hip/hip_bf16.h>

#define NN 200000
#define NE 600000
#define NG 10000
#define NCH 98  // scan chunks of 2048 covering NN

typedef __attribute__((ext_vector_type(8))) short bfrag;
typedef __attribute__((ext_vector_type(4))) float f32x4;
typedef unsigned short u16;

static __device__ __forceinline__ u16 f2b(float x) {
  __hip_bfloat16 b = __float2bfloat16(x);
  return __builtin_bit_cast(u16, b);
}
static __device__ __forceinline__ float b2f(u16 u) {
  __hip_bfloat16 b = __builtin_bit_cast(__hip_bfloat16, u);
  return __bfloat162float(b);
}
static __device__ __forceinline__ void split(float v, u16& hi, u16& lo) {
  hi = f2b(v);
  lo = f2b(v - b2f(hi));
}

// ---------------- weight prep: per-lane MFMA B-fragments, bf16 hi+lo ------
__global__ void prep_kernel(const float* __restrict__ W1_0, const float* __restrict__ W2_0,
                            const float* __restrict__ W1s, const float* __restrict__ W2s,
                            u16* __restrict__ wf) {
  int i = blockIdx.x * 256 + threadIdx.x;
  if (i >= 312 * 64) return;
  int t = i >> 6, lane = i & 63;
  const float* W;
  int KS, ct, kk, Krows, base, half;
  if (t < 24) {
    W = W1_0; KS = 3; ct = t / 3; kk = t - ct * 3; Krows = 78; base = 0; half = 12288;
  } else if (t < 56) {
    int u = t - 24;
    W = W2_0; KS = 4; ct = u >> 2; kk = u & 3; Krows = 128; base = 24576; half = 16384;
  } else {
    int u = t - 56;
    int j = u >> 6, r = u & 63;
    KS = 4; Krows = 128; half = 16384;
    if (r < 32) {
      W = W1s + j * 16384; ct = r >> 2; kk = r & 3; base = 57344 + j * 65536;
    } else {
      W = W2s + j * 16384; r -= 32; ct = r >> 2; kk = r & 3; base = 57344 + j * 65536 + 32768;
    }
  }
  int col = ct * 16 + (lane & 15);
  int idx = ((ct * KS + kk) * 64 + lane) * 8;
  for (int jj = 0; jj < 8; jj++) {
    int k = kk * 32 + 8 * (lane >> 4) + jj;
    float v = (k < Krows) ? W[k * 128 + col] : 0.f;
    u16 hi, lo;
    split(v, hi, lo);
    wf[base + idx + jj] = hi;
    wf[base + half + idx + jj] = lo;
  }
}

// ---------------- CSR build: histogram + scan + scatter -------------------
__global__ void hist_kernel(const int* __restrict__ dst, int* __restrict__ deg) {
  int e = blockIdx.x * 256 + threadIdx.x;
  if (e < NE) atomicAdd(&deg[dst[e]], 1);
}

__global__ void scan1_kernel(const int* __restrict__ deg, int* __restrict__ csum) {
  __shared__ int s[256];
  int base = blockIdx.x * 2048 + threadIdx.x * 8;
  int t = 0;
#pragma unroll
  for (int j = 0; j < 8; j++) {
    int idx = base + j;
    if (idx < NN) t += deg[idx];
  }
  s[threadIdx.x] = t;
  __syncthreads();
  for (int o = 128; o > 0; o >>= 1) {
    if (threadIdx.x < o) s[threadIdx.x] += s[threadIdx.x + o];
    __syncthreads();
  }
  if (threadIdx.x == 0) csum[blockIdx.x] = s[0];
}

__global__ void scan2_kernel(int* __restrict__ csum, int* __restrict__ rowptr) {
  int acc = 0;
  for (int i = 0; i < NCH; i++) {
    int v = csum[i];
    csum[i] = acc;
    acc += v;
  }
  rowptr[NN] = acc;  // == NE
}

// NOTE: deg and cursor may alias (each index read-then-written by one thread).
__global__ void scan3_kernel(const int* deg, const int* __restrict__ csum,
                             int* __restrict__ rowptr, int* cursor) {
  __shared__ int s[256];
  int tid = threadIdx.x;
  int base = blockIdx.x * 2048 + tid * 8;
  int loc[8];
  int t = 0;
#pragma unroll
  for (int j = 0; j < 8; j++) {
    int idx = base + j;
    int d = (idx < NN) ? deg[idx] : 0;
    loc[j] = t;
    t += d;
  }
  s[tid] = t;
  __syncthreads();
  for (int o = 1; o < 256; o <<= 1) {
    int u = (tid >= o) ? s[tid - o] : 0;
    __syncthreads();
    s[tid] += u;
    __syncthreads();
  }
  int off = csum[blockIdx.x] + s[tid] - t;
#pragma unroll
  for (int j = 0; j < 8; j++) {
    int idx = base + j;
    if (idx < NN) {
      int r = off + loc[j];
      rowptr[idx] = r;
      cursor[idx] = r;
    }
  }
}

__global__ void scatter_kernel(const int* __restrict__ src, const int* __restrict__ dst,
                               int* __restrict__ cursor, int* __restrict__ csr_src) {
  int e = blockIdx.x * 256 + threadIdx.x;
  if (e < NE) {
    int p = atomicAdd(&cursor[dst[e]], 1);
    csr_src[p] = src[e];
  }
}

// ---------------- aggregation: CSR gather-sum, one wave per node ----------
template <bool FIRST>
__global__ void agg_csr_kernel(const int* __restrict__ rowptr, const int* __restrict__ csr_src,
                               const float* __restrict__ x, const float* __restrict__ h,
                               const float* __restrict__ ss, float* __restrict__ agg) {
  int node = blockIdx.x * 4 + (threadIdx.x >> 6);
  int lane = threadIdx.x & 63;
  if (node >= NN) return;
  int beg = rowptr[node], end = rowptr[node + 1];
  int f0 = 2 * lane;
  if (FIRST) {
    if (f0 >= 78) return;
    float a0 = 0.f, a1 = 0.f;
    for (int i = beg; i < end; i++) {
      int s = csr_src[i];
      const float2 v = *reinterpret_cast<const float2*>(&x[(size_t)s * 78 + f0]);
      a0 += v.x;
      a1 += v.y;
    }
    float2 o = {a0, a1};
    *reinterpret_cast<float2*>(&agg[(size_t)node * 78 + f0]) = o;
  } else {
    float a0 = 0.f, a1 = 0.f;
    for (int i = beg; i < end; i++) {
      int s = csr_src[i];
      const float2 v = *reinterpret_cast<const float2*>(&h[(size_t)s * 128 + f0]);
      a0 += v.x;
      a1 += v.y;
    }
    float cnt = (float)(end - beg);
    float2 o;
    o.x = a0 * ss[f0] + cnt * ss[128 + f0];
    o.y = a1 * ss[f0 + 1] + cnt * ss[128 + f0 + 1];
    *reinterpret_cast<float2*>(&agg[(size_t)node * 128 + f0]) = o;
  }
}

// ---------------- fused MLP block: column-partitioned, weight-light -------
// 512 threads (8 waves); wave w owns output col-tile ct=w (16 cols) for all
// 64 rows of the tile. Grid-stride over 3125 row-tiles; BN stats in regs.
// NOTE: hout may alias agg (same rows only; agg fully consumed before write).
template <bool FIRST>
__global__ __launch_bounds__(512, 4) void mlp_kernel(
    const float* __restrict__ xin, const float* __restrict__ hin,
    const float* __restrict__ ss, const float* __restrict__ agg,
    const u16* __restrict__ w1hi, const u16* __restrict__ w1lo,
    const u16* __restrict__ w2hi, const u16* __restrict__ w2lo,
    const float* __restrict__ b1, const float* __restrict__ b2,
    float* __restrict__ hout, float* __restrict__ stats) {
  constexpr int KS1 = FIRST ? 3 : 4;
  constexpr int AH = 0, AL = 8704, TH = 17408, TL = 26112;
  __shared__ u16 lds[34816];
  const int tid = threadIdx.x;
  const int w = tid >> 6, l = tid & 63;
  const int l15 = l & 15, lg = l >> 4;
  const float bb1 = b1[w * 16 + l15];
  const float bb2 = b2[w * 16 + l15];
  float s_acc = 0.f, q_acc = 0.f;

  for (int tile = blockIdx.x; tile < 3125; tile += gridDim.x) {
    const int rows0 = tile * 64;
    // ---- stage A = h_bn + agg as bf16 hi/lo ----
    if (FIRST) {
      for (int i = tid; i < 64 * 96; i += 512) {
        int r = i / 96, k = i - r * 96;
        float v = 0.f;
        if (k < 78) {
          int g = rows0 + r;
          v = xin[g * 78 + k] + agg[g * 78 + k];
        }
        u16 hi, lo;
        split(v, hi, lo);
        lds[AH + r * 136 + k] = hi;
        lds[AL + r * 136 + k] = lo;
      }
    } else {
      for (int i = tid; i < 64 * 32; i += 512) {
        int r = i >> 5, k4 = (i & 31) * 4;
        int g = rows0 + r;
        const float4 a4 = *reinterpret_cast<const float4*>(&agg[g * 128 + k4]);
        const float4 h4 = *reinterpret_cast<const float4*>(&hin[g * 128 + k4]);
        float v0 = h4.x * ss[k4 + 0] + ss[128 + k4 + 0] + a4.x;
        float v1 = h4.y * ss[k4 + 1] + ss[128 + k4 + 1] + a4.y;
        float v2 = h4.z * ss[k4 + 2] + ss[128 + k4 + 2] + a4.z;
        float v3 = h4.w * ss[k4 + 3] + ss[128 + k4 + 3] + a4.w;
        ushort4 oh, ol;
        split(v0, oh.x, ol.x);
        split(v1, oh.y, ol.y);
        split(v2, oh.z, ol.z);
        split(v3, oh.w, ol.w);
        *reinterpret_cast<ushort4*>(&lds[AH + r * 136 + k4]) = oh;
        *reinterpret_cast<ushort4*>(&lds[AL + r * 136 + k4]) = ol;
      }
    }
    // ---- W1 frags for this wave's ct (coalesced, out of MFMA chain) ----
    bfrag w1h[KS1], w1l[KS1];
#pragma unroll
    for (int kk = 0; kk < KS1; kk++) {
      int fi = ((w * KS1 + kk) * 64 + l) * 8;
      w1h[kk] = *reinterpret_cast<const bfrag*>(&w1hi[fi]);
      w1l[kk] = *reinterpret_cast<const bfrag*>(&w1lo[fi]);
    }
    __syncthreads();

    // ---- GEMM1: T[:, ct] = relu(A @ W1[:, ct] + b1), 4 independent chains
#pragma unroll
    for (int rt = 0; rt < 4; rt++) {
      f32x4 acc = {bb1, bb1, bb1, bb1};
      const int arow = (rt * 16 + l15) * 136 + 8 * lg;
#pragma unroll
      for (int kk = 0; kk < KS1; kk++) {
        bfrag ah = *reinterpret_cast<const bfrag*>(&lds[AH + arow + kk * 32]);
        bfrag al = *reinterpret_cast<const bfrag*>(&lds[AL + arow + kk * 32]);
        acc = __builtin_amdgcn_mfma_f32_16x16x32_bf16(al, w1h[kk], acc, 0, 0, 0);
        acc = __builtin_amdgcn_mfma_f32_16x16x32_bf16(ah, w1l[kk], acc, 0, 0, 0);
        acc = __builtin_amdgcn_mfma_f32_16x16x32_bf16(ah, w1h[kk], acc, 0, 0, 0);
      }
#pragma unroll
      for (int r = 0; r < 4; r++) {
        float v = fmaxf(acc[r], 0.f);
        u16 hi, lo;
        split(v, hi, lo);
        int off = (rt * 16 + 4 * lg + r) * 136 + w * 16 + l15;
        lds[TH + off] = hi;
        lds[TL + off] = lo;
      }
    }
    // ---- W2 frags ----
    bfrag w2h[4], w2l[4];
#pragma unroll
    for (int kk = 0; kk < 4; kk++) {
      int fi = ((w * 4 + kk) * 64 + l) * 8;
      w2h[kk] = *reinterpret_cast<const bfrag*>(&w2hi[fi]);
      w2l[kk] = *reinterpret_cast<const bfrag*>(&w2lo[fi]);
    }
    __syncthreads();

    // ---- GEMM2: h[:, ct] = relu(T @ W2[:, ct] + b2), stats in regs ----
#pragma unroll
    for (int rt = 0; rt < 4; rt++) {
      f32x4 acc = {bb2, bb2, bb2, bb2};
      const int arow = (rt * 16 + l15) * 136 + 8 * lg;
#pragma unroll
      for (int kk = 0; kk < 4; kk++) {
        bfrag th = *reinterpret_cast<const bfrag*>(&lds[TH + arow + kk * 32]);
        bfrag tl = *reinterpret_cast<const bfrag*>(&lds[TL + arow + kk * 32]);
        acc = __builtin_amdgcn_mfma_f32_16x16x32_bf16(tl, w2h[kk], acc, 0, 0, 0);
        acc = __builtin_amdgcn_mfma_f32_16x16x32_bf16(th, w2l[kk], acc, 0, 0, 0);
        acc = __builtin_amdgcn_mfma_f32_16x16x32_bf16(th, w2h[kk], acc, 0, 0, 0);
      }
#pragma unroll
      for (int r = 0; r < 4; r++) {
        float v = fmaxf(acc[r], 0.f);
        hout[(size_t)(rows0 + rt * 16 + 4 * lg + r) * 128 + w * 16 + l15] = v;
        s_acc += v;
        q_acc += v * v;
      }
    }
    __syncthreads();
  }
  // ---- flush BN stats (once per block) ----
  s_acc += __shfl_xor(s_acc, 16);
  s_acc += __shfl_xor(s_acc, 32);
  q_acc += __shfl_xor(q_acc, 16);
  q_acc += __shfl_xor(q_acc, 32);
  if (lg == 0) {
    atomicAdd(&stats[w * 16 + l15], s_acc);
    atomicAdd(&stats[128 + w * 16 + l15], q_acc);
  }
}

// ---------------- BN finalize -------------------------------------------
__global__ void bn_kernel(const float* __restrict__ stats, const float* __restrict__ gamma,
                          const float* __restrict__ beta, float* __restrict__ ss) {
  int c = threadIdx.x;  // 128 threads
  float mean = stats[c] * (1.f / NN);
  float var = stats[128 + c] * (1.f / NN) - mean * mean;
  var = fmaxf(var, 0.f);
  float sc = gamma[c] * rsqrtf(var + 1e-5f);
  ss[c] = sc;
  ss[128 + c] = beta[c] - mean * sc;
}

// ---------------- pooling: run-based segmented sum (batch is sorted) ------
__global__ void pool_kernel(const float* __restrict__ h, const float* __restrict__ ss,
                            const int* __restrict__ batch, float* __restrict__ pooled) {
  int c = threadIdx.x;  // 128 threads, one feature each
  int n0 = blockIdx.x * 128;
  int n1 = min(n0 + 128, NN);
  float sc = ss[c], sh = ss[128 + c];
  float acc = 0.f;
  float cnt = 0.f;
  int gprev = batch[n0];
  for (int n = n0; n < n1; n++) {
    int g = batch[n];
    if (g != gprev) {
      atomicAdd(&pooled[gprev * 128 + c], sc * acc + cnt * sh);
      acc = 0.f;
      cnt = 0.f;
      gprev = g;
    }
    acc += h[(size_t)n * 128 + c];
    cnt += 1.f;
  }
  atomicAdd(&pooled[gprev * 128 + c], sc * acc + cnt * sh);
}

// ---------------- final FC ------------------------------------------------
__global__ void fc_kernel(const float* __restrict__ pooled, const float* __restrict__ fcW,
                          const float* __restrict__ fcb, float* __restrict__ out) {
  int i = blockIdx.x * 256 + threadIdx.x;
  if (i >= NG * 64) return;
  int g = i >> 6, o = i & 63;
  float acc = fcb[o];
#pragma unroll 8
  for (int k = 0; k < 128; k++) acc += pooled[g * 128 + k] * fcW[k * 64 + o];
  out[i] = fmaxf(acc, 0.f);
}

extern "C" void kernel_launch(void* const* d_in, const int* in_sizes, int n_in,
                              void* d_out, int out_size, void* d_ws, size_t ws_size,
                              hipStream_t stream) {
  const float* x = (const float*)d_in[0];
  const int* ei = (const int*)d_in[1];
  const int* src = ei;
  const int* dst = ei + NE;
  const int* batch = (const int*)d_in[2];
  const float* W1_0 = (const float*)d_in[3];
  const float* b1_0 = (const float*)d_in[4];
  const float* W2_0 = (const float*)d_in[5];
  const float* b2_0 = (const float*)d_in[6];
  const float* g_0 = (const float*)d_in[7];
  const float* be_0 = (const float*)d_in[8];
  const float* W1s = (const float*)d_in[9];
  const float* b1s = (const float*)d_in[10];
  const float* W2s = (const float*)d_in[11];
  const float* b2s = (const float*)d_in[12];
  const float* gs = (const float*)d_in[13];
  const float* bes = (const float*)d_in[14];
  const float* fcW = (const float*)d_in[15];
  const float* fcb = (const float*)d_in[16];

  char* ws = (char*)d_ws;
  float* buf0 = (float*)(ws + 0);                   // 102,400,000 B
  float* buf1 = (float*)(ws + 102400000);           // 102,400,000 B
  float* POOLED = (float*)(ws + 204800000);         // 5,120,000 B
  float* STATS = (float*)(ws + 209920000);          // 1,024 B
  float* SS = (float*)(ws + 209921024);             // 1,024 B
  u16* WF = (u16*)(ws + 209922048);                 // 638,976 B
  int* ROWPTR = (int*)(ws + 210561024);             // 800,016 B
  int* CURSOR = (int*)(ws + 211361040);             // 800,000 B (also deg scratch)
  int* CSRC = (int*)(ws + 212161040);               // 2,400,000 B
  int* CSUM = (int*)(ws + 214561040);               // 512 B

  prep_kernel<<<78, 256, 0, stream>>>(W1_0, W2_0, W1s, W2s, WF);

  // ---- CSR build (once per launch; reused by all 5 layers) ----
  hipMemsetAsync(CURSOR, 0, NN * 4, stream);
  hist_kernel<<<(NE + 255) / 256, 256, 0, stream>>>(dst, CURSOR);
  scan1_kernel<<<NCH, 256, 0, stream>>>(CURSOR, CSUM);
  scan2_kernel<<<1, 1, 0, stream>>>(CSUM, ROWPTR);
  scan3_kernel<<<NCH, 256, 0, stream>>>(CURSOR, CSUM, ROWPTR, CURSOR);
  scatter_kernel<<<(NE + 255) / 256, 256, 0, stream>>>(src, dst, CURSOR, CSRC);

  float* buf[2] = {buf0, buf1};
  // ---- layer 0: agg(x) -> buf1 (78 cols); h0 -> buf0 ----
  hipMemsetAsync(STATS, 0, 1024, stream);
  agg_csr_kernel<true><<<(NN + 3) / 4, 256, 0, stream>>>(ROWPTR, CSRC, x, nullptr, nullptr, buf1);
  mlp_kernel<true><<<512, 512, 0, stream>>>(x, nullptr, nullptr, buf1,
                                            WF, WF + 12288, WF + 24576, WF + 40960,
                                            b1_0, b2_0, buf0, STATS);
  bn_kernel<<<1, 128, 0, stream>>>(STATS, g_0, be_0, SS);

  // ---- layers 1..4 ----
  for (int L = 1; L < 5; L++) {
    int j = L - 1;
    const float* hin = buf[(L + 1) & 1];
    float* hb = buf[L & 1];
    hipMemsetAsync(STATS, 0, 1024, stream);
    agg_csr_kernel<false><<<(NN + 3) / 4, 256, 0, stream>>>(ROWPTR, CSRC, nullptr, hin, SS, hb);
    const u16* wl = WF + 57344 + j * 65536;
    mlp_kernel<false><<<512, 512, 0, stream>>>(nullptr, hin, SS, hb,
                                               wl, wl + 16384, wl + 32768, wl + 49152,
                                               b1s + j * 128, b2s + j * 128, hb, STATS);
    bn_kernel<<<1, 128, 0, stream>>>(STATS, gs + j * 128, bes + j * 128, SS);
  }

  hipMemsetAsync(POOLED, 0, (size_t)NG * 128 * 4, stream);
  pool_kernel<<<(NN + 127) / 128, 128, 0, stream>>>(buf[0], SS, batch, POOLED);
  fc_kernel<<<(NG * 64 + 255) / 256, 256, 0, stream>>>(POOLED, fcW, fcb, (float*)d_out);
}

// Round 5
// 752.765 us; speedup vs baseline: 3.3259x; 1.2245x over previous
//
#include <hip/hip_runtime.h>
#include <hip/hip_bf16.h>

#define NN 200000
#define NE 600000
#define NG 10000
#define NCH 98  // scan chunks of 2048 covering NN

typedef __attribute__((ext_vector_type(8))) short bfrag;
typedef __attribute__((ext_vector_type(4))) float f32x4;
typedef unsigned short u16;

static __device__ __forceinline__ u16 f2b(float x) {
  __hip_bfloat16 b = __float2bfloat16(x);
  return __builtin_bit_cast(u16, b);
}
static __device__ __forceinline__ float b2f(u16 u) {
  __hip_bfloat16 b = __builtin_bit_cast(__hip_bfloat16, u);
  return __bfloat162float(b);
}
static __device__ __forceinline__ void split(float v, u16& hi, u16& lo) {
  hi = f2b(v);
  lo = f2b(v - b2f(hi));
}

// ---------------- weight prep: per-lane MFMA B-fragments, bf16 hi+lo ------
__global__ void prep_kernel(const float* __restrict__ W1_0, const float* __restrict__ W2_0,
                            const float* __restrict__ W1s, const float* __restrict__ W2s,
                            u16* __restrict__ wf) {
  int i = blockIdx.x * 256 + threadIdx.x;
  if (i >= 312 * 64) return;
  int t = i >> 6, lane = i & 63;
  const float* W;
  int KS, ct, kk, Krows, base, half;
  if (t < 24) {
    W = W1_0; KS = 3; ct = t / 3; kk = t - ct * 3; Krows = 78; base = 0; half = 12288;
  } else if (t < 56) {
    int u = t - 24;
    W = W2_0; KS = 4; ct = u >> 2; kk = u & 3; Krows = 128; base = 24576; half = 16384;
  } else {
    int u = t - 56;
    int j = u >> 6, r = u & 63;
    KS = 4; Krows = 128; half = 16384;
    if (r < 32) {
      W = W1s + j * 16384; ct = r >> 2; kk = r & 3; base = 57344 + j * 65536;
    } else {
      W = W2s + j * 16384; r -= 32; ct = r >> 2; kk = r & 3; base = 57344 + j * 65536 + 32768;
    }
  }
  int col = ct * 16 + (lane & 15);
  int idx = ((ct * KS + kk) * 64 + lane) * 8;
  for (int jj = 0; jj < 8; jj++) {
    int k = kk * 32 + 8 * (lane >> 4) + jj;
    float v = (k < Krows) ? W[k * 128 + col] : 0.f;
    u16 hi, lo;
    split(v, hi, lo);
    wf[base + idx + jj] = hi;
    wf[base + half + idx + jj] = lo;
  }
}

// ---------------- CSR build: histogram + scan + scatter -------------------
__global__ void hist_kernel(const int* __restrict__ dst, int* __restrict__ deg) {
  int e = blockIdx.x * 256 + threadIdx.x;
  if (e < NE) atomicAdd(&deg[dst[e]], 1);
}

__global__ void scan1_kernel(const int* __restrict__ deg, int* __restrict__ csum) {
  __shared__ int s[256];
  int base = blockIdx.x * 2048 + threadIdx.x * 8;
  int t = 0;
#pragma unroll
  for (int j = 0; j < 8; j++) {
    int idx = base + j;
    if (idx < NN) t += deg[idx];
  }
  s[threadIdx.x] = t;
  __syncthreads();
  for (int o = 128; o > 0; o >>= 1) {
    if (threadIdx.x < o) s[threadIdx.x] += s[threadIdx.x + o];
    __syncthreads();
  }
  if (threadIdx.x == 0) csum[blockIdx.x] = s[0];
}

__global__ void scan2_kernel(int* __restrict__ csum, int* __restrict__ rowptr) {
  int acc = 0;
  for (int i = 0; i < NCH; i++) {
    int v = csum[i];
    csum[i] = acc;
    acc += v;
  }
  rowptr[NN] = acc;  // == NE
}

// NOTE: deg and cursor may alias (each index read-then-written by one thread).
__global__ void scan3_kernel(const int* deg, const int* __restrict__ csum,
                             int* __restrict__ rowptr, int* cursor) {
  __shared__ int s[256];
  int tid = threadIdx.x;
  int base = blockIdx.x * 2048 + tid * 8;
  int loc[8];
  int t = 0;
#pragma unroll
  for (int j = 0; j < 8; j++) {
    int idx = base + j;
    int d = (idx < NN) ? deg[idx] : 0;
    loc[j] = t;
    t += d;
  }
  s[tid] = t;
  __syncthreads();
  for (int o = 1; o < 256; o <<= 1) {
    int u = (tid >= o) ? s[tid - o] : 0;
    __syncthreads();
    s[tid] += u;
    __syncthreads();
  }
  int off = csum[blockIdx.x] + s[tid] - t;
#pragma unroll
  for (int j = 0; j < 8; j++) {
    int idx = base + j;
    if (idx < NN) {
      int r = off + loc[j];
      rowptr[idx] = r;
      cursor[idx] = r;
    }
  }
}

__global__ void scatter_kernel(const int* __restrict__ src, const int* __restrict__ dst,
                               int* __restrict__ cursor, int* __restrict__ csr_src) {
  int e = blockIdx.x * 256 + threadIdx.x;
  if (e < NE) {
    int p = atomicAdd(&cursor[dst[e]], 1);
    csr_src[p] = src[e];
  }
}

// ---------------- fused GIN block: gather + 2x split-MFMA GEMM + stats ----
// 512 threads (8 waves). Wave w owns output col-tile ct=w and stages rows
// [w*8, w*8+8) of the 64-row tile. Grid-stride; BN stats in registers.
// hout must NOT alias hin (gather reads arbitrary hin rows).
template <bool FIRST>
__global__ __launch_bounds__(512, 4) void fused_kernel(
    const float* __restrict__ xin, const float* __restrict__ hin,
    const float* __restrict__ ss,
    const int* __restrict__ rowptr, const int* __restrict__ csr_src,
    const u16* __restrict__ w1hi, const u16* __restrict__ w1lo,
    const u16* __restrict__ w2hi, const u16* __restrict__ w2lo,
    const float* __restrict__ b1, const float* __restrict__ b2,
    float* __restrict__ hout, float* __restrict__ stats) {
  constexpr int KS1 = FIRST ? 3 : 4;
  constexpr int AH = 0, AL = 8704, TH = 17408, TL = 26112;
  __shared__ u16 lds[34816];
  const int tid = threadIdx.x;
  const int w = tid >> 6, l = tid & 63;
  const int l15 = l & 15, lg = l >> 4;
  const float bb1 = b1[w * 16 + l15];
  const float bb2 = b2[w * 16 + l15];
  float s_acc = 0.f, q_acc = 0.f;

  // per-lane BN affine constants for staging (layout fixed across tiles)
  float4 sc4, sh4;
  if (!FIRST) {
    int k4 = (l & 31) * 4;
    sc4 = *reinterpret_cast<const float4*>(&ss[k4]);
    sh4 = *reinterpret_cast<const float4*>(&ss[128 + k4]);
  }

  for (int tile = blockIdx.x; tile < 3125; tile += gridDim.x) {
    const int rows0 = tile * 64;

    // ---- stage A = self + sum(neighbors), BN-affine, split to hi/lo ----
    if (FIRST) {
      // one row at a time; float2 per lane (lanes 0..38 active for data)
      const float2* x2 = reinterpret_cast<const float2*>(xin);
      for (int j = 0; j < 8; j++) {
        int row = w * 8 + j;
        int node = rows0 + row;
        int beg = rowptr[node], end = rowptr[node + 1];
        int f0 = l * 2;
        if (f0 < 78) {
          size_t fid = (size_t)node * 39 + (f0 >> 1);
          float2 acc = x2[fid];
          int i = beg;
          for (; i + 1 < end; i += 2) {
            int s0 = csr_src[i], s1 = csr_src[i + 1];
            float2 v0 = x2[(size_t)s0 * 39 + (f0 >> 1)];
            float2 v1 = x2[(size_t)s1 * 39 + (f0 >> 1)];
            acc.x += v0.x + v1.x;
            acc.y += v0.y + v1.y;
          }
          if (i < end) {
            int s0 = csr_src[i];
            float2 v0 = x2[(size_t)s0 * 39 + (f0 >> 1)];
            acc.x += v0.x;
            acc.y += v0.y;
          }
          ushort2 oh, ol;
          split(acc.x, oh.x, ol.x);
          split(acc.y, oh.y, ol.y);
          *reinterpret_cast<ushort2*>(&lds[AH + row * 136 + f0]) = oh;
          *reinterpret_cast<ushort2*>(&lds[AL + row * 136 + f0]) = ol;
        } else if (f0 < 96) {
          ushort2 z = {0, 0};
          *reinterpret_cast<ushort2*>(&lds[AH + row * 136 + f0]) = z;
          *reinterpret_cast<ushort2*>(&lds[AL + row * 136 + f0]) = z;
        }
      }
    } else {
      // two rows at a time (lane halves); float4 per lane
      const float4* h4p = reinterpret_cast<const float4*>(hin);
      int k4 = (l & 31) * 4;
      for (int p = 0; p < 4; p++) {
        int row = w * 8 + p * 2 + (l >> 5);
        int node = rows0 + row;
        int beg = rowptr[node], end = rowptr[node + 1];
        size_t foff = (size_t)(k4 >> 2);
        float4 acc = h4p[(size_t)node * 32 + foff];  // self
        int i = beg;
        for (; i + 1 < end; i += 2) {
          int s0 = csr_src[i], s1 = csr_src[i + 1];
          float4 v0 = h4p[(size_t)s0 * 32 + foff];
          float4 v1 = h4p[(size_t)s1 * 32 + foff];
          acc.x += v0.x + v1.x;
          acc.y += v0.y + v1.y;
          acc.z += v0.z + v1.z;
          acc.w += v0.w + v1.w;
        }
        if (i < end) {
          int s0 = csr_src[i];
          float4 v0 = h4p[(size_t)s0 * 32 + foff];
          acc.x += v0.x;
          acc.y += v0.y;
          acc.z += v0.z;
          acc.w += v0.w;
        }
        float cnt = (float)(end - beg + 1);
        float a0 = acc.x * sc4.x + cnt * sh4.x;
        float a1 = acc.y * sc4.y + cnt * sh4.y;
        float a2 = acc.z * sc4.z + cnt * sh4.z;
        float a3 = acc.w * sc4.w + cnt * sh4.w;
        ushort4 oh, ol;
        split(a0, oh.x, ol.x);
        split(a1, oh.y, ol.y);
        split(a2, oh.z, ol.z);
        split(a3, oh.w, ol.w);
        *reinterpret_cast<ushort4*>(&lds[AH + row * 136 + k4]) = oh;
        *reinterpret_cast<ushort4*>(&lds[AL + row * 136 + k4]) = ol;
      }
    }
    // ---- W1 frags for this wave's col-tile ----
    bfrag w1h[KS1], w1l[KS1];
#pragma unroll
    for (int kk = 0; kk < KS1; kk++) {
      int fi = ((w * KS1 + kk) * 64 + l) * 8;
      w1h[kk] = *reinterpret_cast<const bfrag*>(&w1hi[fi]);
      w1l[kk] = *reinterpret_cast<const bfrag*>(&w1lo[fi]);
    }
    __syncthreads();

    // ---- GEMM1: T[:, ct] = relu(A @ W1[:, ct] + b1) ----
#pragma unroll
    for (int rt = 0; rt < 4; rt++) {
      f32x4 acc = {bb1, bb1, bb1, bb1};
      const int arow = (rt * 16 + l15) * 136 + 8 * lg;
#pragma unroll
      for (int kk = 0; kk < KS1; kk++) {
        bfrag ah = *reinterpret_cast<const bfrag*>(&lds[AH + arow + kk * 32]);
        bfrag al = *reinterpret_cast<const bfrag*>(&lds[AL + arow + kk * 32]);
        acc = __builtin_amdgcn_mfma_f32_16x16x32_bf16(al, w1h[kk], acc, 0, 0, 0);
        acc = __builtin_amdgcn_mfma_f32_16x16x32_bf16(ah, w1l[kk], acc, 0, 0, 0);
        acc = __builtin_amdgcn_mfma_f32_16x16x32_bf16(ah, w1h[kk], acc, 0, 0, 0);
      }
#pragma unroll
      for (int r = 0; r < 4; r++) {
        float v = fmaxf(acc[r], 0.f);
        u16 hi, lo;
        split(v, hi, lo);
        int off = (rt * 16 + 4 * lg + r) * 136 + w * 16 + l15;
        lds[TH + off] = hi;
        lds[TL + off] = lo;
      }
    }
    // ---- W2 frags ----
    bfrag w2h[4], w2l[4];
#pragma unroll
    for (int kk = 0; kk < 4; kk++) {
      int fi = ((w * 4 + kk) * 64 + l) * 8;
      w2h[kk] = *reinterpret_cast<const bfrag*>(&w2hi[fi]);
      w2l[kk] = *reinterpret_cast<const bfrag*>(&w2lo[fi]);
    }
    __syncthreads();

    // ---- GEMM2: h[:, ct] = relu(T @ W2[:, ct] + b2), stats in regs ----
#pragma unroll
    for (int rt = 0; rt < 4; rt++) {
      f32x4 acc = {bb2, bb2, bb2, bb2};
      const int arow = (rt * 16 + l15) * 136 + 8 * lg;
#pragma unroll
      for (int kk = 0; kk < 4; kk++) {
        bfrag th = *reinterpret_cast<const bfrag*>(&lds[TH + arow + kk * 32]);
        bfrag tl = *reinterpret_cast<const bfrag*>(&lds[TL + arow + kk * 32]);
        acc = __builtin_amdgcn_mfma_f32_16x16x32_bf16(tl, w2h[kk], acc, 0, 0, 0);
        acc = __builtin_amdgcn_mfma_f32_16x16x32_bf16(th, w2l[kk], acc, 0, 0, 0);
        acc = __builtin_amdgcn_mfma_f32_16x16x32_bf16(th, w2h[kk], acc, 0, 0, 0);
      }
#pragma unroll
      for (int r = 0; r < 4; r++) {
        float v = fmaxf(acc[r], 0.f);
        hout[(size_t)(rows0 + rt * 16 + 4 * lg + r) * 128 + w * 16 + l15] = v;
        s_acc += v;
        q_acc += v * v;
      }
    }
    __syncthreads();
  }
  // ---- flush BN stats (once per block) ----
  s_acc += __shfl_xor(s_acc, 16);
  s_acc += __shfl_xor(s_acc, 32);
  q_acc += __shfl_xor(q_acc, 16);
  q_acc += __shfl_xor(q_acc, 32);
  if (lg == 0) {
    atomicAdd(&stats[w * 16 + l15], s_acc);
    atomicAdd(&stats[128 + w * 16 + l15], q_acc);
  }
}

// ---------------- BN finalize -------------------------------------------
__global__ void bn_kernel(const float* __restrict__ stats, const float* __restrict__ gamma,
                          const float* __restrict__ beta, float* __restrict__ ss) {
  int c = threadIdx.x;  // 128 threads
  float mean = stats[c] * (1.f / NN);
  float var = stats[128 + c] * (1.f / NN) - mean * mean;
  var = fmaxf(var, 0.f);
  float sc = gamma[c] * rsqrtf(var + 1e-5f);
  ss[c] = sc;
  ss[128 + c] = beta[c] - mean * sc;
}

// ---------------- pooling: run-based segmented sum (batch is sorted) ------
__global__ void pool_kernel(const float* __restrict__ h, const float* __restrict__ ss,
                            const int* __restrict__ batch, float* __restrict__ pooled) {
  int c = threadIdx.x;  // 128 threads, one feature each
  int n0 = blockIdx.x * 128;
  int n1 = min(n0 + 128, NN);
  float sc = ss[c], sh = ss[128 + c];
  float acc = 0.f;
  float cnt = 0.f;
  int gprev = batch[n0];
  for (int n = n0; n < n1; n++) {
    int g = batch[n];
    if (g != gprev) {
      atomicAdd(&pooled[gprev * 128 + c], sc * acc + cnt * sh);
      acc = 0.f;
      cnt = 0.f;
      gprev = g;
    }
    acc += h[(size_t)n * 128 + c];
    cnt += 1.f;
  }
  atomicAdd(&pooled[gprev * 128 + c], sc * acc + cnt * sh);
}

// ---------------- final FC ------------------------------------------------
__global__ void fc_kernel(const float* __restrict__ pooled, const float* __restrict__ fcW,
                          const float* __restrict__ fcb, float* __restrict__ out) {
  int i = blockIdx.x * 256 + threadIdx.x;
  if (i >= NG * 64) return;
  int g = i >> 6, o = i & 63;
  float acc = fcb[o];
#pragma unroll 8
  for (int k = 0; k < 128; k++) acc += pooled[g * 128 + k] * fcW[k * 64 + o];
  out[i] = fmaxf(acc, 0.f);
}

extern "C" void kernel_launch(void* const* d_in, const int* in_sizes, int n_in,
                              void* d_out, int out_size, void* d_ws, size_t ws_size,
                              hipStream_t stream) {
  const float* x = (const float*)d_in[0];
  const int* ei = (const int*)d_in[1];
  const int* src = ei;
  const int* dst = ei + NE;
  const int* batch = (const int*)d_in[2];
  const float* W1_0 = (const float*)d_in[3];
  const float* b1_0 = (const float*)d_in[4];
  const float* W2_0 = (const float*)d_in[5];
  const float* b2_0 = (const float*)d_in[6];
  const float* g_0 = (const float*)d_in[7];
  const float* be_0 = (const float*)d_in[8];
  const float* W1s = (const float*)d_in[9];
  const float* b1s = (const float*)d_in[10];
  const float* W2s = (const float*)d_in[11];
  const float* b2s = (const float*)d_in[12];
  const float* gs = (const float*)d_in[13];
  const float* bes = (const float*)d_in[14];
  const float* fcW = (const float*)d_in[15];
  const float* fcb = (const float*)d_in[16];

  char* ws = (char*)d_ws;
  float* buf0 = (float*)(ws + 0);                   // 102,400,000 B
  float* buf1 = (float*)(ws + 102400000);           // 102,400,000 B
  float* POOLED = (float*)(ws + 204800000);         // 5,120,000 B
  float* STATS = (float*)(ws + 209920000);          // 1,024 B
  float* SS = (float*)(ws + 209921024);             // 1,024 B
  u16* WF = (u16*)(ws + 209922048);                 // 638,976 B
  int* ROWPTR = (int*)(ws + 210561024);             // 800,016 B
  int* CURSOR = (int*)(ws + 211361040);             // 800,000 B (also deg scratch)
  int* CSRC = (int*)(ws + 212161040);               // 2,400,000 B
  int* CSUM = (int*)(ws + 214561040);               // 512 B

  prep_kernel<<<78, 256, 0, stream>>>(W1_0, W2_0, W1s, W2s, WF);

  // ---- CSR build (once per launch; reused by all 5 layers) ----
  hipMemsetAsync(CURSOR, 0, NN * 4, stream);
  hist_kernel<<<(NE + 255) / 256, 256, 0, stream>>>(dst, CURSOR);
  scan1_kernel<<<NCH, 256, 0, stream>>>(CURSOR, CSUM);
  scan2_kernel<<<1, 1, 0, stream>>>(CSUM, ROWPTR);
  scan3_kernel<<<NCH, 256, 0, stream>>>(CURSOR, CSUM, ROWPTR, CURSOR);
  scatter_kernel<<<(NE + 255) / 256, 256, 0, stream>>>(src, dst, CURSOR, CSRC);

  float* buf[2] = {buf0, buf1};
  // ---- layer 0: x -> buf0 ----
  hipMemsetAsync(STATS, 0, 1024, stream);
  fused_kernel<true><<<512, 512, 0, stream>>>(x, nullptr, nullptr, ROWPTR, CSRC,
                                              WF, WF + 12288, WF + 24576, WF + 40960,
                                              b1_0, b2_0, buf0, STATS);
  bn_kernel<<<1, 128, 0, stream>>>(STATS, g_0, be_0, SS);

  // ---- layers 1..4: ping-pong buf0 <-> buf1 ----
  for (int L = 1; L < 5; L++) {
    int j = L - 1;
    const float* hin = buf[(L + 1) & 1];
    float* hb = buf[L & 1];
    hipMemsetAsync(STATS, 0, 1024, stream);
    const u16* wl = WF + 57344 + j * 65536;
    fused_kernel<false><<<512, 512, 0, stream>>>(nullptr, hin, SS, ROWPTR, CSRC,
                                                 wl, wl + 16384, wl + 32768, wl + 49152,
                                                 b1s + j * 128, b2s + j * 128, hb, STATS);
    bn_kernel<<<1, 128, 0, stream>>>(STATS, gs + j * 128, bes + j * 128, SS);
  }

  hipMemsetAsync(POOLED, 0, (size_t)NG * 128 * 4, stream);
  pool_kernel<<<(NN + 127) / 128, 128, 0, stream>>>(buf[0], SS, batch, POOLED);
  fc_kernel<<<(NG * 64 + 255) / 256, 256, 0, stream>>>(POOLED, fcW, fcb, (float*)d_out);
}

// Round 6
// 690.948 us; speedup vs baseline: 3.6235x; 1.0895x over previous
//
#include <hip/hip_runtime.h>
#include <hip/hip_bf16.h>

#define NN 200000
#define NE 600000
#define NG 10000
#define NCH 98  // scan chunks of 2048 covering NN

typedef __attribute__((ext_vector_type(8))) short bfrag;
typedef __attribute__((ext_vector_type(4))) float f32x4;
typedef unsigned short u16;

static __device__ __forceinline__ u16 f2b(float x) {
  __hip_bfloat16 b = __float2bfloat16(x);
  return __builtin_bit_cast(u16, b);
}
static __device__ __forceinline__ float b2f(u16 u) {
  __hip_bfloat16 b = __builtin_bit_cast(__hip_bfloat16, u);
  return __bfloat162float(b);
}
static __device__ __forceinline__ void split(float v, u16& hi, u16& lo) {
  hi = f2b(v);
  lo = f2b(v - b2f(hi));
}

// ---------------- weight prep: per-lane MFMA B-fragments, bf16 hi+lo ------
__global__ void prep_kernel(const float* __restrict__ W1_0, const float* __restrict__ W2_0,
                            const float* __restrict__ W1s, const float* __restrict__ W2s,
                            u16* __restrict__ wf) {
  int i = blockIdx.x * 256 + threadIdx.x;
  if (i >= 312 * 64) return;
  int t = i >> 6, lane = i & 63;
  const float* W;
  int KS, ct, kk, Krows, base, half;
  if (t < 24) {
    W = W1_0; KS = 3; ct = t / 3; kk = t - ct * 3; Krows = 78; base = 0; half = 12288;
  } else if (t < 56) {
    int u = t - 24;
    W = W2_0; KS = 4; ct = u >> 2; kk = u & 3; Krows = 128; base = 24576; half = 16384;
  } else {
    int u = t - 56;
    int j = u >> 6, r = u & 63;
    KS = 4; Krows = 128; half = 16384;
    if (r < 32) {
      W = W1s + j * 16384; ct = r >> 2; kk = r & 3; base = 57344 + j * 65536;
    } else {
      W = W2s + j * 16384; r -= 32; ct = r >> 2; kk = r & 3; base = 57344 + j * 65536 + 32768;
    }
  }
  int col = ct * 16 + (lane & 15);
  int idx = ((ct * KS + kk) * 64 + lane) * 8;
  for (int jj = 0; jj < 8; jj++) {
    int k = kk * 32 + 8 * (lane >> 4) + jj;
    float v = (k < Krows) ? W[k * 128 + col] : 0.f;
    u16 hi, lo;
    split(v, hi, lo);
    wf[base + idx + jj] = hi;
    wf[base + half + idx + jj] = lo;
  }
}

// ---------------- CSR build: histogram + scan + scatter -------------------
__global__ void hist_kernel(const int* __restrict__ dst, int* __restrict__ deg) {
  int e = blockIdx.x * 256 + threadIdx.x;
  if (e < NE) atomicAdd(&deg[dst[e]], 1);
}

__global__ void scan1_kernel(const int* __restrict__ deg, int* __restrict__ csum) {
  __shared__ int s[256];
  int base = blockIdx.x * 2048 + threadIdx.x * 8;
  int t = 0;
#pragma unroll
  for (int j = 0; j < 8; j++) {
    int idx = base + j;
    if (idx < NN) t += deg[idx];
  }
  s[threadIdx.x] = t;
  __syncthreads();
  for (int o = 128; o > 0; o >>= 1) {
    if (threadIdx.x < o) s[threadIdx.x] += s[threadIdx.x + o];
    __syncthreads();
  }
  if (threadIdx.x == 0) csum[blockIdx.x] = s[0];
}

__global__ void scan2_kernel(int* __restrict__ csum, int* __restrict__ rowptr) {
  int acc = 0;
  for (int i = 0; i < NCH; i++) {
    int v = csum[i];
    csum[i] = acc;
    acc += v;
  }
  rowptr[NN] = acc;  // == NE
}

// NOTE: deg and cursor may alias (each index read-then-written by one thread).
__global__ void scan3_kernel(const int* deg, const int* __restrict__ csum,
                             int* __restrict__ rowptr, int* cursor) {
  __shared__ int s[256];
  int tid = threadIdx.x;
  int base = blockIdx.x * 2048 + tid * 8;
  int loc[8];
  int t = 0;
#pragma unroll
  for (int j = 0; j < 8; j++) {
    int idx = base + j;
    int d = (idx < NN) ? deg[idx] : 0;
    loc[j] = t;
    t += d;
  }
  s[tid] = t;
  __syncthreads();
  for (int o = 1; o < 256; o <<= 1) {
    int u = (tid >= o) ? s[tid - o] : 0;
    __syncthreads();
    s[tid] += u;
    __syncthreads();
  }
  int off = csum[blockIdx.x] + s[tid] - t;
#pragma unroll
  for (int j = 0; j < 8; j++) {
    int idx = base + j;
    if (idx < NN) {
      int r = off + loc[j];
      rowptr[idx] = r;
      cursor[idx] = r;
    }
  }
}

__global__ void scatter_kernel(const int* __restrict__ src, const int* __restrict__ dst,
                               int* __restrict__ cursor, int* __restrict__ csr_src) {
  int e = blockIdx.x * 256 + threadIdx.x;
  if (e < NE) {
    int p = atomicAdd(&cursor[dst[e]], 1);
    csr_src[p] = src[e];
  }
}

// ---------------- fused GIN block: gather + 2x split-MFMA GEMM + stats ----
// 512 threads (8 waves). Wave w owns output col-tile ct=w and stages rows
// [w*8, w*8+8). h stored bf16 (256B rows): 16-lane groups, ushort8/lane,
// 4 rows per pass, neighbor loop unrolled x4. Grid-stride; stats in regs.
// hout must NOT alias hin (gather reads arbitrary hin rows).
template <bool FIRST>
__global__ __launch_bounds__(512, 4) void fused_kernel(
    const float* __restrict__ xin, const u16* __restrict__ hin,
    const float* __restrict__ ss,
    const int* __restrict__ rowptr, const int* __restrict__ csr_src,
    const u16* __restrict__ w1hi, const u16* __restrict__ w1lo,
    const u16* __restrict__ w2hi, const u16* __restrict__ w2lo,
    const float* __restrict__ b1, const float* __restrict__ b2,
    u16* __restrict__ hout, float* __restrict__ stats) {
  constexpr int KS1 = FIRST ? 3 : 4;
  constexpr int AH = 0, AL = 8704, TH = 17408, TL = 26112;
  __shared__ u16 lds[34816];
  const int tid = threadIdx.x;
  const int w = tid >> 6, l = tid & 63;
  const int l15 = l & 15, lg = l >> 4;
  const float bb1 = b1[w * 16 + l15];
  const float bb2 = b2[w * 16 + l15];
  float s_acc = 0.f, q_acc = 0.f;

  // per-lane BN affine constants for staging (fixed layout across tiles)
  float sc8[8], sh8[8];
  if (!FIRST) {
    int k8 = l15 * 8;
#pragma unroll
    for (int j = 0; j < 8; j++) {
      sc8[j] = ss[k8 + j];
      sh8[j] = ss[128 + k8 + j];
    }
  }

  for (int tile = blockIdx.x; tile < 3125; tile += gridDim.x) {
    const int rows0 = tile * 64;

    // ---- stage A = self + sum(neighbors), BN-affine, split to hi/lo ----
    if (FIRST) {
      // x is f32 [NN][78]; float2 per lane, one row per wave-pass
      const float2* x2 = reinterpret_cast<const float2*>(xin);
      for (int j = 0; j < 8; j++) {
        int row = w * 8 + j;
        int node = rows0 + row;
        int beg = rowptr[node], end = rowptr[node + 1];
        int f0 = l * 2;
        if (f0 < 78) {
          size_t fid = (size_t)node * 39 + (f0 >> 1);
          float2 acc = x2[fid];
          int i = beg;
          for (; i + 1 < end; i += 2) {
            int s0 = csr_src[i], s1 = csr_src[i + 1];
            float2 v0 = x2[(size_t)s0 * 39 + (f0 >> 1)];
            float2 v1 = x2[(size_t)s1 * 39 + (f0 >> 1)];
            acc.x += v0.x + v1.x;
            acc.y += v0.y + v1.y;
          }
          if (i < end) {
            int s0 = csr_src[i];
            float2 v0 = x2[(size_t)s0 * 39 + (f0 >> 1)];
            acc.x += v0.x;
            acc.y += v0.y;
          }
          ushort2 oh, ol;
          split(acc.x, oh.x, ol.x);
          split(acc.y, oh.y, ol.y);
          *reinterpret_cast<ushort2*>(&lds[AH + row * 136 + f0]) = oh;
          *reinterpret_cast<ushort2*>(&lds[AL + row * 136 + f0]) = ol;
        } else if (f0 < 96) {
          ushort2 z = {0, 0};
          *reinterpret_cast<ushort2*>(&lds[AH + row * 136 + f0]) = z;
          *reinterpret_cast<ushort2*>(&lds[AL + row * 136 + f0]) = z;
        }
      }
    } else {
      // h is bf16 [NN][128]; 16-lane row groups, ushort8 (16B) per lane
      const bfrag* hp = reinterpret_cast<const bfrag*>(hin);
      const int k8v = l15;  // vector index within row (8 bf16 each)
      for (int p = 0; p < 2; p++) {
        int row = w * 8 + p * 4 + lg;
        int node = rows0 + row;
        int beg = rowptr[node], end = rowptr[node + 1];
        float a[8];
        bfrag vs = hp[(size_t)node * 16 + k8v];  // self
#pragma unroll
        for (int j = 0; j < 8; j++) a[j] = b2f((u16)vs[j]);
        int i = beg;
        for (; i + 3 < end; i += 4) {
          int s0 = csr_src[i], s1 = csr_src[i + 1];
          int s2 = csr_src[i + 2], s3 = csr_src[i + 3];
          bfrag v0 = hp[(size_t)s0 * 16 + k8v];
          bfrag v1 = hp[(size_t)s1 * 16 + k8v];
          bfrag v2 = hp[(size_t)s2 * 16 + k8v];
          bfrag v3 = hp[(size_t)s3 * 16 + k8v];
#pragma unroll
          for (int j = 0; j < 8; j++)
            a[j] += (b2f((u16)v0[j]) + b2f((u16)v1[j])) + (b2f((u16)v2[j]) + b2f((u16)v3[j]));
        }
        for (; i < end; i++) {
          int s0 = csr_src[i];
          bfrag v0 = hp[(size_t)s0 * 16 + k8v];
#pragma unroll
          for (int j = 0; j < 8; j++) a[j] += b2f((u16)v0[j]);
        }
        float cnt = (float)(end - beg + 1);
        bfrag oh, ol;
#pragma unroll
        for (int j = 0; j < 8; j++) {
          float t = a[j] * sc8[j] + cnt * sh8[j];
          u16 hi, lo;
          split(t, hi, lo);
          oh[j] = (short)hi;
          ol[j] = (short)lo;
        }
        *reinterpret_cast<bfrag*>(&lds[AH + row * 136 + l15 * 8]) = oh;
        *reinterpret_cast<bfrag*>(&lds[AL + row * 136 + l15 * 8]) = ol;
      }
    }
    // ---- W1 frags for this wave's col-tile ----
    bfrag w1h[KS1], w1l[KS1];
#pragma unroll
    for (int kk = 0; kk < KS1; kk++) {
      int fi = ((w * KS1 + kk) * 64 + l) * 8;
      w1h[kk] = *reinterpret_cast<const bfrag*>(&w1hi[fi]);
      w1l[kk] = *reinterpret_cast<const bfrag*>(&w1lo[fi]);
    }
    __syncthreads();

    // ---- GEMM1: T[:, ct] = relu(A @ W1[:, ct] + b1) ----
#pragma unroll
    for (int rt = 0; rt < 4; rt++) {
      f32x4 acc = {bb1, bb1, bb1, bb1};
      const int arow = (rt * 16 + l15) * 136 + 8 * lg;
#pragma unroll
      for (int kk = 0; kk < KS1; kk++) {
        bfrag ah = *reinterpret_cast<const bfrag*>(&lds[AH + arow + kk * 32]);
        bfrag al = *reinterpret_cast<const bfrag*>(&lds[AL + arow + kk * 32]);
        acc = __builtin_amdgcn_mfma_f32_16x16x32_bf16(al, w1h[kk], acc, 0, 0, 0);
        acc = __builtin_amdgcn_mfma_f32_16x16x32_bf16(ah, w1l[kk], acc, 0, 0, 0);
        acc = __builtin_amdgcn_mfma_f32_16x16x32_bf16(ah, w1h[kk], acc, 0, 0, 0);
      }
#pragma unroll
      for (int r = 0; r < 4; r++) {
        float v = fmaxf(acc[r], 0.f);
        u16 hi, lo;
        split(v, hi, lo);
        int off = (rt * 16 + 4 * lg + r) * 136 + w * 16 + l15;
        lds[TH + off] = hi;
        lds[TL + off] = lo;
      }
    }
    // ---- W2 frags ----
    bfrag w2h[4], w2l[4];
#pragma unroll
    for (int kk = 0; kk < 4; kk++) {
      int fi = ((w * 4 + kk) * 64 + l) * 8;
      w2h[kk] = *reinterpret_cast<const bfrag*>(&w2hi[fi]);
      w2l[kk] = *reinterpret_cast<const bfrag*>(&w2lo[fi]);
    }
    __syncthreads();

    // ---- GEMM2: h[:, ct] = relu(T @ W2[:, ct] + b2), bf16 out, stats ----
#pragma unroll
    for (int rt = 0; rt < 4; rt++) {
      f32x4 acc = {bb2, bb2, bb2, bb2};
      const int arow = (rt * 16 + l15) * 136 + 8 * lg;
#pragma unroll
      for (int kk = 0; kk < 4; kk++) {
        bfrag th = *reinterpret_cast<const bfrag*>(&lds[TH + arow + kk * 32]);
        bfrag tl = *reinterpret_cast<const bfrag*>(&lds[TL + arow + kk * 32]);
        acc = __builtin_amdgcn_mfma_f32_16x16x32_bf16(tl, w2h[kk], acc, 0, 0, 0);
        acc = __builtin_amdgcn_mfma_f32_16x16x32_bf16(th, w2l[kk], acc, 0, 0, 0);
        acc = __builtin_amdgcn_mfma_f32_16x16x32_bf16(th, w2h[kk], acc, 0, 0, 0);
      }
#pragma unroll
      for (int r = 0; r < 4; r++) {
        float v = fmaxf(acc[r], 0.f);
        hout[(size_t)(rows0 + rt * 16 + 4 * lg + r) * 128 + w * 16 + l15] = f2b(v);
        s_acc += v;
        q_acc += v * v;
      }
    }
    __syncthreads();
  }
  // ---- flush BN stats (once per block) ----
  s_acc += __shfl_xor(s_acc, 16);
  s_acc += __shfl_xor(s_acc, 32);
  q_acc += __shfl_xor(q_acc, 16);
  q_acc += __shfl_xor(q_acc, 32);
  if (lg == 0) {
    atomicAdd(&stats[w * 16 + l15], s_acc);
    atomicAdd(&stats[128 + w * 16 + l15], q_acc);
  }
}

// ---------------- BN finalize -------------------------------------------
__global__ void bn_kernel(const float* __restrict__ stats, const float* __restrict__ gamma,
                          const float* __restrict__ beta, float* __restrict__ ss) {
  int c = threadIdx.x;  // 128 threads
  float mean = stats[c] * (1.f / NN);
  float var = stats[128 + c] * (1.f / NN) - mean * mean;
  var = fmaxf(var, 0.f);
  float sc = gamma[c] * rsqrtf(var + 1e-5f);
  ss[c] = sc;
  ss[128 + c] = beta[c] - mean * sc;
}

// ---------------- pooling: run-based segmented sum (batch is sorted) ------
__global__ void pool_kernel(const u16* __restrict__ h, const float* __restrict__ ss,
                            const int* __restrict__ batch, float* __restrict__ pooled) {
  int c = threadIdx.x;  // 128 threads, one feature each
  int n0 = blockIdx.x * 128;
  int n1 = min(n0 + 128, NN);
  float sc = ss[c], sh = ss[128 + c];
  float acc = 0.f;
  float cnt = 0.f;
  int gprev = batch[n0];
  for (int n = n0; n < n1; n++) {
    int g = batch[n];
    if (g != gprev) {
      atomicAdd(&pooled[gprev * 128 + c], sc * acc + cnt * sh);
      acc = 0.f;
      cnt = 0.f;
      gprev = g;
    }
    acc += b2f(h[(size_t)n * 128 + c]);
    cnt += 1.f;
  }
  atomicAdd(&pooled[gprev * 128 + c], sc * acc + cnt * sh);
}

// ---------------- final FC ------------------------------------------------
__global__ void fc_kernel(const float* __restrict__ pooled, const float* __restrict__ fcW,
                          const float* __restrict__ fcb, float* __restrict__ out) {
  int i = blockIdx.x * 256 + threadIdx.x;
  if (i >= NG * 64) return;
  int g = i >> 6, o = i & 63;
  float acc = fcb[o];
#pragma unroll 8
  for (int k = 0; k < 128; k++) acc += pooled[g * 128 + k] * fcW[k * 64 + o];
  out[i] = fmaxf(acc, 0.f);
}

extern "C" void kernel_launch(void* const* d_in, const int* in_sizes, int n_in,
                              void* d_out, int out_size, void* d_ws, size_t ws_size,
                              hipStream_t stream) {
  const float* x = (const float*)d_in[0];
  const int* ei = (const int*)d_in[1];
  const int* src = ei;
  const int* dst = ei + NE;
  const int* batch = (const int*)d_in[2];
  const float* W1_0 = (const float*)d_in[3];
  const float* b1_0 = (const float*)d_in[4];
  const float* W2_0 = (const float*)d_in[5];
  const float* b2_0 = (const float*)d_in[6];
  const float* g_0 = (const float*)d_in[7];
  const float* be_0 = (const float*)d_in[8];
  const float* W1s = (const float*)d_in[9];
  const float* b1s = (const float*)d_in[10];
  const float* W2s = (const float*)d_in[11];
  const float* b2s = (const float*)d_in[12];
  const float* gs = (const float*)d_in[13];
  const float* bes = (const float*)d_in[14];
  const float* fcW = (const float*)d_in[15];
  const float* fcb = (const float*)d_in[16];

  char* ws = (char*)d_ws;
  u16* buf0 = (u16*)(ws + 0);                       // 51,200,000 B
  u16* buf1 = (u16*)(ws + 51200000);                // 51,200,000 B
  float* POOLED = (float*)(ws + 102400000);         // 5,120,000 B
  float* STATS = (float*)(ws + 107520000);          // 1,024 B
  float* SS = (float*)(ws + 107521024);             // 1,024 B
  u16* WF = (u16*)(ws + 107522048);                 // 638,976 B
  int* ROWPTR = (int*)(ws + 108161024);             // 800,016 B
  int* CURSOR = (int*)(ws + 108961040);             // 800,000 B (also deg scratch)
  int* CSRC = (int*)(ws + 109761040);               // 2,400,000 B
  int* CSUM = (int*)(ws + 112161040);               // 512 B

  prep_kernel<<<78, 256, 0, stream>>>(W1_0, W2_0, W1s, W2s, WF);

  // ---- CSR build (once per launch; reused by all 5 layers) ----
  hipMemsetAsync(CURSOR, 0, NN * 4, stream);
  hist_kernel<<<(NE + 255) / 256, 256, 0, stream>>>(dst, CURSOR);
  scan1_kernel<<<NCH, 256, 0, stream>>>(CURSOR, CSUM);
  scan2_kernel<<<1, 1, 0, stream>>>(CSUM, ROWPTR);
  scan3_kernel<<<NCH, 256, 0, stream>>>(CURSOR, CSUM, ROWPTR, CURSOR);
  scatter_kernel<<<(NE + 255) / 256, 256, 0, stream>>>(src, dst, CURSOR, CSRC);

  u16* buf[2] = {buf0, buf1};
  // ---- layer 0: x -> buf0 ----
  hipMemsetAsync(STATS, 0, 1024, stream);
  fused_kernel<true><<<512, 512, 0, stream>>>(x, nullptr, nullptr, ROWPTR, CSRC,
                                              WF, WF + 12288, WF + 24576, WF + 40960,
                                              b1_0, b2_0, buf0, STATS);
  bn_kernel<<<1, 128, 0, stream>>>(STATS, g_0, be_0, SS);

  // ---- layers 1..4: ping-pong buf0 <-> buf1 ----
  for (int L = 1; L < 5; L++) {
    int j = L - 1;
    const u16* hin = buf[(L + 1) & 1];
    u16* hb = buf[L & 1];
    hipMemsetAsync(STATS, 0, 1024, stream);
    const u16* wl = WF + 57344 + j * 65536;
    fused_kernel<false><<<512, 512, 0, stream>>>(nullptr, hin, SS, ROWPTR, CSRC,
                                                 wl, wl + 16384, wl + 32768, wl + 49152,
                                                 b1s + j * 128, b2s + j * 128, hb, STATS);
    bn_kernel<<<1, 128, 0, stream>>>(STATS, gs + j * 128, bes + j * 128, SS);
  }

  hipMemsetAsync(POOLED, 0, (size_t)NG * 128 * 4, stream);
  pool_kernel<<<(NN + 127) / 128, 128, 0, stream>>>(buf[0], SS, batch, POOLED);
  fc_kernel<<<(NG * 64 + 255) / 256, 256, 0, stream>>>(POOLED, fcW, fcb, (float*)d_out);
}